// Round 1
// baseline (172.188 us; speedup 1.0000x reference)
//
#include <hip/hip_runtime.h>

#define Bn 8
#define Nn 16384
#define Cn 256

typedef __attribute__((ext_vector_type(4)))  float f32x4;
typedef __attribute__((ext_vector_type(16))) float f32x16;
typedef __attribute__((ext_vector_type(8)))  __bf16 bf16x8;
typedef __attribute__((ext_vector_type(8)))  unsigned short u16x8;

static __device__ __forceinline__ unsigned short f2bf(float f) {
    unsigned int u = __float_as_uint(f);
    u += 0x7fff + ((u >> 16) & 1);          // RNE
    return (unsigned short)(u >> 16);
}
static __device__ __forceinline__ float bf2f(unsigned short h) {
    return __uint_as_float(((unsigned int)h) << 16);
}
static __device__ __forceinline__ f32x16 mfma16(u16x8 a, u16x8 b, f32x16 c) {
    return __builtin_amdgcn_mfma_f32_32x32x16_bf16(
        __builtin_bit_cast(bf16x8, a), __builtin_bit_cast(bf16x8, b), c, 0, 0, 0);
}

// ---------------- K1: Gram partials (hi/lo bf16, 3 MFMA per tile) + row sums ----------------
__global__ __launch_bounds__(512, 2) void k_gram(
    const float* __restrict__ x, float* __restrict__ gpart,
    float* __restrict__ spart, int NC) {
  const int blk = blockIdx.x;
  const int b  = blk / NC;
  const int ck = blk - b * NC;
  const int chunk = Nn / NC;
  const int nst   = chunk >> 6;           // stages of 64 columns
  const float* xb = x + (size_t)b * Cn * Nn + (size_t)ck * chunk;

  __shared__ __align__(16) char smem[65536];   // h: [0,32K), l: [32K,64K), rows of 128B

  const int t    = threadIdx.x;
  const int lane = t & 63;
  const int w    = t >> 6;
  const int wm = w & 1, wn = w >> 1;      // wave tile: rows wm*128, cols wn*64
  const int ln = lane & 31;
  const int kh = lane >> 5;

  f32x16 acc[4][2];
#pragma unroll
  for (int m = 0; m < 4; ++m)
#pragma unroll
    for (int n = 0; n < 2; ++n)
#pragma unroll
      for (int i = 0; i < 16; ++i) acc[m][n][i] = 0.f;

  const int rt = t >> 4;    // 0..31
  const int c4 = t & 15;    // float4 group within 64-col stage

  float srow[8];
  f32x4 ld[8];
#pragma unroll
  for (int j = 0; j < 8; ++j) {
    srow[j] = 0.f;
    ld[j] = *(const f32x4*)(xb + (size_t)(rt + 32 * j) * Nn + c4 * 4);
  }

  for (int s = 0; s < nst; ++s) {
    ushort4 h4[8], l4[8];
#pragma unroll
    for (int j = 0; j < 8; ++j) {
      f32x4 v = ld[j];
      srow[j] += v.x + v.y + v.z + v.w;
      unsigned short hx = f2bf(v.x), hy = f2bf(v.y), hz = f2bf(v.z), hw = f2bf(v.w);
      h4[j] = make_ushort4(hx, hy, hz, hw);
      l4[j] = make_ushort4(f2bf(v.x - bf2f(hx)), f2bf(v.y - bf2f(hy)),
                           f2bf(v.z - bf2f(hz)), f2bf(v.w - bf2f(hw)));
    }
    __syncthreads();
#pragma unroll
    for (int j = 0; j < 8; ++j) {
      int row = rt + 32 * j;
      int off = row * 128 + ((c4 * 8) ^ ((row & 7) << 4));   // XOR-swizzle (G4)
      *(ushort4*)(smem + off) = h4[j];
      *(ushort4*)(smem + 32768 + off) = l4[j];
    }
    __syncthreads();
    if (s + 1 < nst) {                     // prefetch next stage into regs (overlap w/ MFMA)
#pragma unroll
      for (int j = 0; j < 8; ++j)
        ld[j] = *(const f32x4*)(xb + (size_t)(rt + 32 * j) * Nn + (s + 1) * 64 + c4 * 4);
    }
#pragma unroll
    for (int ks = 0; ks < 4; ++ks) {
      const int koff = ks * 32 + kh * 16;
      u16x8 Ah[4], Al[4], Bh[2], Bl[2];
#pragma unroll
      for (int m = 0; m < 4; ++m) {
        int r = wm * 128 + m * 32 + ln;
        int off = r * 128 + (koff ^ ((r & 7) << 4));
        Ah[m] = *(const u16x8*)(smem + off);
        Al[m] = *(const u16x8*)(smem + 32768 + off);
      }
#pragma unroll
      for (int n = 0; n < 2; ++n) {
        int r = wn * 64 + n * 32 + ln;
        int off = r * 128 + (koff ^ ((r & 7) << 4));
        Bh[n] = *(const u16x8*)(smem + off);
        Bl[n] = *(const u16x8*)(smem + 32768 + off);
      }
#pragma unroll
      for (int m = 0; m < 4; ++m)
#pragma unroll
        for (int n = 0; n < 2; ++n) {
          acc[m][n] = mfma16(Ah[m], Bh[n], acc[m][n]);   // G = HH^T + HL^T + LH^T
          acc[m][n] = mfma16(Ah[m], Bl[n], acc[m][n]);
          acc[m][n] = mfma16(Al[m], Bh[n], acc[m][n]);
        }
    }
  }

  // row-sum reduce across the 16 threads that share a row
#pragma unroll
  for (int j = 0; j < 8; ++j) {
    float v = srow[j];
    v += __shfl_xor(v, 1);
    v += __shfl_xor(v, 2);
    v += __shfl_xor(v, 4);
    v += __shfl_xor(v, 8);
    if ((t & 15) == 0)
      spart[(size_t)(b * NC + ck) * Cn + rt + 32 * j] = v;
  }

  float* gp = gpart + (size_t)(b * NC + ck) * (Cn * Cn);
#pragma unroll
  for (int m = 0; m < 4; ++m)
#pragma unroll
    for (int n = 0; n < 2; ++n)
#pragma unroll
      for (int r = 0; r < 16; ++r) {
        int row = wm * 128 + m * 32 + (r & 3) + 8 * (r >> 2) + 4 * kh;
        int col = wn * 64 + n * 32 + ln;
        gp[row * Cn + col] = acc[m][n][r];
      }
}

// ---------------- K2: reduce Gram partials + row sums; transpose Wk ----------------
__global__ __launch_bounds__(256) void k_reduce(
    const float* __restrict__ gpart, const float* __restrict__ spart,
    const float* __restrict__ wk, float* __restrict__ G,
    float* __restrict__ sv, float* __restrict__ wkT, int NC) {
  const int blk = blockIdx.x, t = threadIdx.x;
  if (blk < 512) {
    const int i4 = blk * 256 + t;         // float4 index into [B][256][256]
    const int b  = i4 >> 14;
    const int r  = i4 & 16383;
    const f32x4* base = (const f32x4*)gpart + (size_t)b * NC * 16384 + r;
    f32x4 a = base[0];
    for (int ck = 1; ck < NC; ++ck) a += base[(size_t)ck * 16384];
    ((f32x4*)G)[i4] = a;
  } else {
    const int bb = blk - 512;             // 0..7
    float a = 0.f;
    for (int ck = 0; ck < NC; ++ck) a += spart[(size_t)(bb * NC + ck) * Cn + t];
    sv[bb * Cn + t] = a;
#pragma unroll
    for (int j = 0; j < 32; ++j) {
      int k = bb * 32 + j;
      wkT[k * Cn + t] = wk[t * Cn + k];
    }
  }
}

// ---------------- K3: scores = Wq G Wk^T + rank-1 bias terms; softmax; ccT(+I) bf16 ----------------
__global__ __launch_bounds__(256) void k_scores(
    const float* __restrict__ G, const float* __restrict__ sv,
    const float* __restrict__ wq, const float* __restrict__ wkT,
    const float* __restrict__ bq, const float* __restrict__ bk,
    unsigned short* __restrict__ ccT) {
  const int b    = blockIdx.x >> 5;
  const int tile = blockIdx.x & 31;
  const int c0   = tile * 8;
  const int t    = threadIdx.x;

  __shared__ float wq_l[8][256];
  __shared__ float m1_l[8][256];
  __shared__ float sc_l[8][256];
  __shared__ float s_l[256];
  __shared__ float qs_l[8];
  __shared__ float bq_l[8];
  __shared__ unsigned short cct_l[256][8];

#pragma unroll
  for (int j = 0; j < 8; ++j) wq_l[j][t] = wq[(c0 + j) * Cn + t];
  s_l[t] = sv[b * Cn + t];
  if (t < 8) bq_l[t] = bq[c0 + t];
  __syncthreads();

  // phase 1: M1[c0+r][t] = sum_k Wq[c0+r,k] G[k,t]
  float a[8];
#pragma unroll
  for (int r = 0; r < 8; ++r) a[r] = 0.f;
  const float* Gb = G + (size_t)b * 65536;
  for (int k = 0; k < 256; ++k) {
    float g = Gb[k * 256 + t];
#pragma unroll
    for (int r = 0; r < 8; ++r) a[r] += wq_l[r][k] * g;
  }
#pragma unroll
  for (int r = 0; r < 8; ++r) m1_l[r][t] = a[r];

  if (t < 8) {
    float q = 0.f;
    for (int c = 0; c < 256; ++c) q += wq_l[t][c] * s_l[c];
    qs_l[t] = q;                          // (Wq s)[c0+t]
  }
  float kst = 0.f;                        // (Wk s)[t]
  for (int c = 0; c < 256; ++c) kst += wkT[c * 256 + t] * s_l[c];
  __syncthreads();

  // phase 2: scores[c0+r][t]
  float sc[8];
#pragma unroll
  for (int r = 0; r < 8; ++r) sc[r] = 0.f;
  for (int k = 0; k < 256; ++k) {
    float wv = wkT[k * 256 + t];
#pragma unroll
    for (int r = 0; r < 8; ++r) sc[r] += m1_l[r][k] * wv;
  }
  float bkt = bk[t];
#pragma unroll
  for (int r = 0; r < 8; ++r)
    sc_l[r][t] = sc[r] + qs_l[r] * bkt + bq_l[r] * (kst + 16384.f * bkt);
  __syncthreads();

  // phase 3: softmax over d, write ccT[d][c] (+1 on diagonal)
  const int r = t >> 5, sub = t & 31;
  float v[8];
#pragma unroll
  for (int j = 0; j < 8; ++j) v[j] = sc_l[r][sub + 32 * j];
  float mx = v[0];
#pragma unroll
  for (int j = 1; j < 8; ++j) mx = fmaxf(mx, v[j]);
#pragma unroll
  for (int msk = 16; msk >= 1; msk >>= 1) mx = fmaxf(mx, __shfl_xor(mx, msk, 32));
  float se = 0.f;
#pragma unroll
  for (int j = 0; j < 8; ++j) { v[j] = __expf(v[j] - mx); se += v[j]; }
#pragma unroll
  for (int msk = 16; msk >= 1; msk >>= 1) se += __shfl_xor(se, msk, 32);
  float inv = 1.f / se;
#pragma unroll
  for (int j = 0; j < 8; ++j) {
    int d = sub + 32 * j;
    float cc = v[j] * inv + ((d == c0 + r) ? 1.f : 0.f);   // fold residual: cc + I
    cct_l[d][r] = f2bf(cc);
  }
  __syncthreads();
  *(uint4*)(ccT + (size_t)b * 65536 + t * 256 + c0) = *(const uint4*)(&cct_l[t][0]);
}

// ---------------- K4: out = x_bf16 @ (cc + I)  (residual folded) ----------------
__global__ __launch_bounds__(256, 2) void k_out(
    const float* __restrict__ x, const unsigned short* __restrict__ ccT,
    float* __restrict__ out) {
  const int blk = blockIdx.x;
  const int b  = blk >> 7;
  const int n0 = (blk & 127) * 128;
  const float* xb = x + (size_t)b * Nn * Cn + (size_t)n0 * Cn;
  const unsigned short* cb = ccT + (size_t)b * 65536;
  float* ob = out + (size_t)b * Nn * Cn + (size_t)n0 * Cn;

  __shared__ __align__(16) char smem[16384];   // [128 rows][128B]

  const int t    = threadIdx.x;
  const int lane = t & 63;
  const int w    = t >> 6;
  const int wm = w & 1, wn = w >> 1;      // wave: rows wm*64, cols wn*128
  const int ln = lane & 31;
  const int kh = lane >> 5;

  f32x16 acc[2][4];
#pragma unroll
  for (int m = 0; m < 2; ++m)
#pragma unroll
    for (int n = 0; n < 4; ++n)
#pragma unroll
      for (int i = 0; i < 16; ++i) acc[m][n][i] = 0.f;

  const int rt = t >> 4;   // 0..15
  const int c4 = t & 15;
  f32x4 ld[8];
#pragma unroll
  for (int j = 0; j < 8; ++j)
    ld[j] = *(const f32x4*)(xb + (size_t)(rt + 16 * j) * Cn + c4 * 4);

  for (int s = 0; s < 4; ++s) {
    ushort4 h4[8];
#pragma unroll
    for (int j = 0; j < 8; ++j)
      h4[j] = make_ushort4(f2bf(ld[j].x), f2bf(ld[j].y), f2bf(ld[j].z), f2bf(ld[j].w));
    __syncthreads();
#pragma unroll
    for (int j = 0; j < 8; ++j) {
      int row = rt + 16 * j;
      int off = row * 128 + ((c4 * 8) ^ ((row & 7) << 4));
      *(ushort4*)(smem + off) = h4[j];
    }
    __syncthreads();
    if (s < 3) {
#pragma unroll
      for (int j = 0; j < 8; ++j)
        ld[j] = *(const f32x4*)(xb + (size_t)(rt + 16 * j) * Cn + (s + 1) * 64 + c4 * 4);
    }
#pragma unroll
    for (int ks = 0; ks < 4; ++ks) {
      const int koff = ks * 32 + kh * 16;
      u16x8 A[2];
#pragma unroll
      for (int m = 0; m < 2; ++m) {
        int r2 = wm * 64 + m * 32 + ln;
        A[m] = *(const u16x8*)(smem + r2 * 128 + (koff ^ ((r2 & 7) << 4)));
      }
      u16x8 Bv[4];
#pragma unroll
      for (int n = 0; n < 4; ++n) {
        int d  = wn * 128 + n * 32 + ln;
        int kk = s * 64 + ks * 16 + kh * 8;
        Bv[n] = *(const u16x8*)(cb + d * 256 + kk);   // ccT: L2-resident, reused by all blocks
      }
#pragma unroll
      for (int m = 0; m < 2; ++m)
#pragma unroll
        for (int n = 0; n < 4; ++n)
          acc[m][n] = mfma16(A[m], Bv[n], acc[m][n]);
    }
  }

#pragma unroll
  for (int m = 0; m < 2; ++m)
#pragma unroll
    for (int n = 0; n < 4; ++n)
#pragma unroll
      for (int r2 = 0; r2 < 16; ++r2) {
        int row = wm * 64 + m * 32 + (r2 & 3) + 8 * (r2 >> 2) + 4 * kh;
        int col = wn * 128 + n * 32 + ln;
        ob[(size_t)row * Cn + col] = acc[m][n][r2];
      }
}

extern "C" void kernel_launch(void* const* d_in, const int* in_sizes, int n_in,
                              void* d_out, int out_size, void* d_ws, size_t ws_size,
                              hipStream_t stream) {
  const float* x  = (const float*)d_in[0];
  const float* wq = (const float*)d_in[1];
  const float* bq = (const float*)d_in[2];
  const float* wk = (const float*)d_in[3];
  const float* bk = (const float*)d_in[4];
  float* out = (float*)d_out;

  // pick split-K factor for the Gram stage based on available workspace
  int NC = 32;
  while (NC > 1) {
    size_t need = (size_t)Bn * NC * 65536 * 4 + (size_t)Bn * NC * 256 * 4
                + (size_t)Bn * 65536 * 4 + (size_t)Bn * 256 * 4
                + (size_t)65536 * 4 + (size_t)Bn * 65536 * 2;
    if (need <= ws_size) break;
    NC >>= 1;
  }

  float* gpart = (float*)d_ws;                          // [B][NC][256][256]
  float* spart = gpart + (size_t)Bn * NC * 65536;       // [B][NC][256]
  float* G     = spart + (size_t)Bn * NC * 256;         // [B][256][256]
  float* sv    = G + (size_t)Bn * 65536;                // [B][256]
  float* wkT   = sv + (size_t)Bn * 256;                 // [256][256]
  unsigned short* ccT = (unsigned short*)(wkT + 65536); // [B][256][256] bf16 (transposed, +I)

  hipLaunchKernelGGL(k_gram,   dim3(Bn * NC), dim3(512), 0, stream, x, gpart, spart, NC);
  hipLaunchKernelGGL(k_reduce, dim3(520),     dim3(256), 0, stream, gpart, spart, wk, G, sv, wkT, NC);
  hipLaunchKernelGGL(k_scores, dim3(256),     dim3(256), 0, stream, G, sv, wq, wkT, bq, bk, ccT);
  hipLaunchKernelGGL(k_out,    dim3(Bn * 128), dim3(256), 0, stream, x, ccT, out);
}